// Round 3
// baseline (542.389 us; speedup 1.0000x reference)
//
#include <hip/hip_runtime.h>
#include <math.h>

// Coverage attention. B=64, S=2048, H=512.
// e_t[b,s] = v_b + sum_h v_w[h] * tanh( (enc@Wh)[b,s,h] + D[b,h] + cov[b,s]*Wc[h] )
//   D[b,h] = (dec @ Ws)[b,h] + bs[h] + bh[h] + bc[h]
// out = [softmax(e_t) | coverage + softmax(e_t)]
//
// R2: barrier-free K-loop. B panel (BN=128 x 256k) persistent in 64KB LDS
// (loaded once per K-half; 3 barriers/block total). A streamed
// HBM->VGPR->bf16->MFMA directly (no A LDS, no staging barriers).
// 512-thr blocks, 2 blocks/CU, launch_bounds(512,4) caps VGPR at 128.
// XOR chunk swizzle on Bs keeps ds_read_b128 frags 2-way (free).

#define B_ 64
#define S_ 2048
#define H_ 512
#define M_ (B_ * S_)

#define BN 128        // n-cols per phase
#define PHASES 4      // H_/BN
#define KH 256        // K per LDS-resident half
#define RPB 256       // rows per block (8 waves x 32)

typedef __attribute__((ext_vector_type(4))) float f32x4;
typedef __attribute__((ext_vector_type(8))) short s16x8;

__device__ __forceinline__ short f2bf(float f) {
    unsigned u = __float_as_uint(f);
    u += 0x7fffu + ((u >> 16) & 1u);  // RNE
    return (short)(u >> 16);
}

__device__ __forceinline__ s16x8 cvt8(float4 a, float4 b) {
    s16x8 r;
    r[0] = f2bf(a.x); r[1] = f2bf(a.y); r[2] = f2bf(a.z); r[3] = f2bf(a.w);
    r[4] = f2bf(b.x); r[5] = f2bf(b.y); r[6] = f2bf(b.z); r[7] = f2bf(b.w);
    return r;
}

__device__ __forceinline__ float fast_tanh(float x) {
    return 1.0f - 2.0f / (__expf(2.0f * x) + 1.0f);  // saturates correctly
}

// Whbt[n][k] = bf16(Wh[k][n])
__global__ __launch_bounds__(256) void transpose_cast(
    const float* __restrict__ Wh, short* __restrict__ Bt) {
    __shared__ float tile[32][33];
    const int n0 = blockIdx.x * 32, k0 = blockIdx.y * 32;
    const int tx = threadIdx.x & 31, ty = threadIdx.x >> 5;  // 32 x 8
#pragma unroll
    for (int r = 0; r < 32; r += 8)
        tile[ty + r][tx] = Wh[(size_t)(k0 + ty + r) * H_ + n0 + tx];
    __syncthreads();
#pragma unroll
    for (int r = 0; r < 32; r += 8)
        Bt[(size_t)(n0 + ty + r) * H_ + k0 + tx] = f2bf(tile[tx][ty + r]);
}

// D[b,h] = dec[b,:] . Ws[:,h] + bs[h] + bh[h] + bc[h]
__global__ __launch_bounds__(512) void dec_kernel(
    const float* __restrict__ dh, const float* __restrict__ Ws,
    const float* __restrict__ bs, const float* __restrict__ bh,
    const float* __restrict__ bc, float* __restrict__ D) {
    const int b = blockIdx.x;
    const int h = threadIdx.x;
    __shared__ float sdh[H_];
    sdh[h] = dh[b * H_ + h];
    __syncthreads();
    float acc = bs[h] + bh[h] + bc[h];
#pragma unroll 8
    for (int k = 0; k < H_; ++k)
        acc = fmaf(sdh[k], Ws[k * H_ + h], acc);
    D[b * H_ + h] = acc;
}

__global__ __launch_bounds__(512, 4) void gemm_fused(
    const float* __restrict__ A,      // [M_, H_] fp32 encoder
    const short* __restrict__ Bt,     // [H_, H_] bf16, [n][k]
    const float* __restrict__ cover,  // [M_]
    const float* __restrict__ Wc,     // [H_]
    const float* __restrict__ vw,     // [H_]
    const float* __restrict__ D,      // [B_, H_]
    float* __restrict__ e_ws) {       // [PHASES][M_]
    __shared__ __align__(16) short Bs[BN * KH];  // 65536 B, chunk-swizzled

    const int tid = threadIdx.x;
    const int w = tid >> 6;
    const int l = tid & 63;
    const int q = l >> 4;    // quad
    const int ml = l & 15;   // m (A) / n (B) within 16-tile

    const int phase = blockIdx.x;       // fastest-varying: L3 row sharing
    const int n0 = phase * BN;
    const int row_blk = blockIdx.y * RPB;
    const int b = row_blk >> 11;        // /S_ (RPB divides S_)
    const int r0 = row_blk + w * 32;    // this wave's 32 rows

    f32x4 acc[2][8];
#pragma unroll
    for (int t = 0; t < 2; ++t)
#pragma unroll
        for (int u = 0; u < 8; ++u) acc[t][u] = (f32x4)0.0f;

    // A stream pointers: m-tile t rows r0+t*16+ml, k = q*8 (+32 per step)
    const float* ap0 = A + (size_t)(r0 + ml) * H_ + q * 8;
    const float* ap1 = ap0 + (size_t)16 * H_;
    float4 pa0 = *(const float4*)ap0;
    float4 pa1 = *(const float4*)(ap0 + 4);
    float4 pa2 = *(const float4*)ap1;
    float4 pa3 = *(const float4*)(ap1 + 4);
    ap0 += 32; ap1 += 32;

    // B staging coords: thread covers row n = tid>>2, chunks cb..cb+7
    const int sn = tid >> 2;
    const int scb = (tid & 3) * 8;
    const short* sg = Bt + (size_t)(n0 + sn) * H_ + scb * 8;
    short* sd = Bs + sn * KH;

    for (int half = 0; half < 2; ++half) {
        if (half) __syncthreads();  // all reads of prev half done
#pragma unroll
        for (int j = 0; j < 8; ++j) {
            const int c = scb + j;
            const int cs = c ^ (sn & 7);
            *(s16x8*)(sd + cs * 8) = *(const s16x8*)(sg + j * 8 + half * KH);
        }
        __syncthreads();

#pragma unroll
        for (int ks = 0; ks < 8; ++ks) {
            const s16x8 a0 = cvt8(pa0, pa1);
            const s16x8 a1 = cvt8(pa2, pa3);
            if (!(half == 1 && ks == 7)) {  // prefetch next k-step (spans restage)
                pa0 = *(const float4*)ap0;
                pa1 = *(const float4*)(ap0 + 4);
                pa2 = *(const float4*)ap1;
                pa3 = *(const float4*)(ap1 + 4);
                ap0 += 32; ap1 += 32;
            }
            const int cbase = ks * 4 + q;  // local 16B-chunk index
#pragma unroll
            for (int uh = 0; uh < 2; ++uh) {
                s16x8 bfr[4];
#pragma unroll
                for (int v = 0; v < 4; ++v) {
                    const int n = (uh * 4 + v) * 16 + ml;
                    bfr[v] = *(const s16x8*)&Bs[n * KH + (cbase ^ (n & 7)) * 8];
                }
#pragma unroll
                for (int v = 0; v < 4; ++v) {
                    acc[0][uh * 4 + v] = __builtin_amdgcn_mfma_f32_16x16x32_bf16(
                        a0, bfr[v], acc[0][uh * 4 + v], 0, 0, 0);
                    acc[1][uh * 4 + v] = __builtin_amdgcn_mfma_f32_16x16x32_bf16(
                        a1, bfr[v], acc[1][uh * 4 + v], 0, 0, 0);
                }
            }
        }
    }

    // ---- epilogue: x = acc + cov*Wc + D; p = sum_n vw*tanh(x)
    // C layout: col = ml (n), row = q*4 + reg (m89-verified)
    float wc[8], vv[8], dd[8];
#pragma unroll
    for (int u = 0; u < 8; ++u) {
        const int n = n0 + u * 16 + ml;
        wc[u] = Wc[n];
        vv[u] = vw[n];
        dd[u] = D[b * H_ + n];
    }
#pragma unroll
    for (int t = 0; t < 2; ++t) {
        const int rb = r0 + t * 16 + q * 4;
        float p0 = 0.f, p1 = 0.f, p2 = 0.f, p3 = 0.f;
        const float cv0 = cover[rb + 0];
        const float cv1 = cover[rb + 1];
        const float cv2 = cover[rb + 2];
        const float cv3 = cover[rb + 3];
#pragma unroll
        for (int u = 0; u < 8; ++u) {
            p0 += vv[u] * fast_tanh(acc[t][u].x + fmaf(cv0, wc[u], dd[u]));
            p1 += vv[u] * fast_tanh(acc[t][u].y + fmaf(cv1, wc[u], dd[u]));
            p2 += vv[u] * fast_tanh(acc[t][u].z + fmaf(cv2, wc[u], dd[u]));
            p3 += vv[u] * fast_tanh(acc[t][u].w + fmaf(cv3, wc[u], dd[u]));
        }
#pragma unroll
        for (int s = 1; s < 16; s <<= 1) {
            p0 += __shfl_xor(p0, s, 64);
            p1 += __shfl_xor(p1, s, 64);
            p2 += __shfl_xor(p2, s, 64);
            p3 += __shfl_xor(p3, s, 64);
        }
        if (ml == 0) {
            float* dst = e_ws + (size_t)phase * M_ + rb;
            dst[0] = p0; dst[1] = p1; dst[2] = p2; dst[3] = p3;
        }
    }
}

__global__ __launch_bounds__(256) void softmax_kernel(
    const float* __restrict__ e_ws, const float* __restrict__ cover,
    const float* __restrict__ vb, float* __restrict__ out) {
    const int b = blockIdx.x;
    const int tid = threadIdx.x;
    const float vbv = vb[0];

    float e[8];
    float mx = -1e30f;
#pragma unroll
    for (int r = 0; r < 8; ++r) {
        const int idx = b * S_ + r * 256 + tid;
        e[r] = e_ws[idx] + e_ws[M_ + idx] + e_ws[2 * M_ + idx] +
               e_ws[3 * M_ + idx] + vbv;
        mx = fmaxf(mx, e[r]);
    }
#pragma unroll
    for (int off = 32; off >= 1; off >>= 1) mx = fmaxf(mx, __shfl_xor(mx, off, 64));

    __shared__ float sm[4], ss[4], sbc[2];
    const int wid = tid >> 6, lane = tid & 63;
    if (lane == 0) sm[wid] = mx;
    __syncthreads();
    if (tid == 0) sbc[0] = fmaxf(fmaxf(sm[0], sm[1]), fmaxf(sm[2], sm[3]));
    __syncthreads();
    mx = sbc[0];

    float ex[8];
    float sum = 0.0f;
#pragma unroll
    for (int r = 0; r < 8; ++r) {
        ex[r] = __expf(e[r] - mx);
        sum += ex[r];
    }
#pragma unroll
    for (int off = 32; off >= 1; off >>= 1) sum += __shfl_xor(sum, off, 64);
    if (lane == 0) ss[wid] = sum;
    __syncthreads();
    if (tid == 0) sbc[1] = ss[0] + ss[1] + ss[2] + ss[3];
    __syncthreads();
    const float inv = 1.0f / sbc[1];

#pragma unroll
    for (int r = 0; r < 8; ++r) {
        const int s = r * 256 + tid;
        const float a = ex[r] * inv;
        out[b * S_ + s] = a;                           // a_t
        out[M_ + b * S_ + s] = cover[b * S_ + s] + a;  // sum_coverage
    }
}

extern "C" void kernel_launch(void* const* d_in, const int* in_sizes, int n_in,
                              void* d_out, int out_size, void* d_ws, size_t ws_size,
                              hipStream_t stream) {
    const float* enc = (const float*)d_in[0];
    const float* dh  = (const float*)d_in[1];
    const float* cov = (const float*)d_in[2];
    const float* Wh  = (const float*)d_in[3];
    const float* bh  = (const float*)d_in[4];
    const float* Ws  = (const float*)d_in[5];
    const float* bs  = (const float*)d_in[6];
    const float* Wc  = (const float*)d_in[7];
    const float* bc  = (const float*)d_in[8];
    const float* vw  = (const float*)d_in[9];
    const float* vb  = (const float*)d_in[10];
    float* out = (float*)d_out;

    float* e_ws = (float*)d_ws;              // PHASES * M_ floats
    float* Dws  = e_ws + PHASES * M_;        // B_*H_ floats
    short* Whbt = (short*)(Dws + B_ * H_);   // H_*H_ bf16

    transpose_cast<<<dim3(H_ / 32, H_ / 32), 256, 0, stream>>>(Wh, Whbt);
    dec_kernel<<<B_, 512, 0, stream>>>(dh, Ws, bs, bh, bc, Dws);
    dim3 g2(PHASES, M_ / RPB);
    gemm_fused<<<g2, 512, 0, stream>>>(enc, Whbt, cov, Wc, vw, Dws, e_ws);
    softmax_kernel<<<B_, 256, 0, stream>>>(e_ws, cov, vb, out);
}

// Round 4
// 491.830 us; speedup vs baseline: 1.1028x; 1.1028x over previous
//
#include <hip/hip_runtime.h>
#include <math.h>

// Coverage attention. B=64, S=2048, H=512.
// e_t[b,s] = v_b + sum_h v_w[h] * tanh( (enc@Wh)[b,s,h] + D[b,h] + cov[b,s]*Wc[h] )
//   D[b,h] = (dec @ Ws)[b,h] + bs[h] + bh[h] + bc[h]
// out = [softmax(e_t) | coverage + softmax(e_t)]
//
// R3: A register-resident. Each wave holds 32 rows x K=512 of A as bf16
// MFMA fragments (128 VGPR), loaded+converted ONCE (A read exactly once
// device-wide = 256 MB HBM floor). B (tiny, L2-hot) cycles through LDS in
// 8 phases of 64n x 512k (64 KB), fragment-order layout with XOR swizzle
// (pos = q*16 + (ml^2q)) -> conflict-free ds_read_b128 AND ds_write_b128.
// k-loop = pure LDS+MFMA. e_t accumulated across phases in registers,
// written once. 256-thr blocks, launch_bounds(256,2), 2 blocks/CU.

#define B_ 64
#define S_ 2048
#define H_ 512
#define M_ (B_ * S_)

#define RPB 128   // rows per block (4 waves x 32)
#define BN 64     // n per phase
#define NPH 8     // phases = H_/BN

typedef __attribute__((ext_vector_type(4))) float f32x4;
typedef __attribute__((ext_vector_type(8))) short s16x8;

__device__ __forceinline__ short f2bf(float f) {
    unsigned u = __float_as_uint(f);
    u += 0x7fffu + ((u >> 16) & 1u);  // RNE
    return (short)(u >> 16);
}

__device__ __forceinline__ s16x8 cvt8(float4 a, float4 b) {
    s16x8 r;
    r[0] = f2bf(a.x); r[1] = f2bf(a.y); r[2] = f2bf(a.z); r[3] = f2bf(a.w);
    r[4] = f2bf(b.x); r[5] = f2bf(b.y); r[6] = f2bf(b.z); r[7] = f2bf(b.w);
    return r;
}

__device__ __forceinline__ float fast_tanh(float x) {
    return 1.0f - 2.0f / (__expf(2.0f * x) + 1.0f);  // saturates correctly
}

// Whbt[n][k] = bf16(Wh[k][n])
__global__ __launch_bounds__(256) void transpose_cast(
    const float* __restrict__ Wh, short* __restrict__ Bt) {
    __shared__ float tile[32][33];
    const int n0 = blockIdx.x * 32, k0 = blockIdx.y * 32;
    const int tx = threadIdx.x & 31, ty = threadIdx.x >> 5;  // 32 x 8
#pragma unroll
    for (int r = 0; r < 32; r += 8)
        tile[ty + r][tx] = Wh[(size_t)(k0 + ty + r) * H_ + n0 + tx];
    __syncthreads();
#pragma unroll
    for (int r = 0; r < 32; r += 8)
        Bt[(size_t)(n0 + ty + r) * H_ + k0 + tx] = f2bf(tile[tx][ty + r]);
}

// D[b,h] = dec[b,:] . Ws[:,h] + bs[h] + bh[h] + bc[h]
__global__ __launch_bounds__(512) void dec_kernel(
    const float* __restrict__ dh, const float* __restrict__ Ws,
    const float* __restrict__ bs, const float* __restrict__ bh,
    const float* __restrict__ bc, float* __restrict__ D) {
    const int b = blockIdx.x;
    const int h = threadIdx.x;
    __shared__ float sdh[H_];
    sdh[h] = dh[b * H_ + h];
    __syncthreads();
    float acc = bs[h] + bh[h] + bc[h];
#pragma unroll 8
    for (int k = 0; k < H_; ++k)
        acc = fmaf(sdh[k], Ws[k * H_ + h], acc);
    D[b * H_ + h] = acc;
}

__global__ __launch_bounds__(256, 2) void gemm_fused(
    const float* __restrict__ A,      // [M_, H_] fp32 encoder
    const short* __restrict__ Bt,     // [H_, H_] bf16, [n][k]
    const float* __restrict__ cover,  // [M_]
    const float* __restrict__ Wc,     // [H_]
    const float* __restrict__ vw,     // [H_]
    const float* __restrict__ D,      // [B_, H_]
    float* __restrict__ e_t) {        // [M_] final logits (minus v_b)
    __shared__ __align__(16) short Bs[BN * H_];  // 65536 B, fragment-order

    const int tid = threadIdx.x;
    const int w = tid >> 6;
    const int l = tid & 63;
    const int q = l >> 4;    // k-quad (A/B) / row-quad (C)
    const int ml = l & 15;   // m (A) / n (B) within 16-tile

    const int row_blk = blockIdx.x * RPB;
    const int b = row_blk >> 11;       // /S_
    const int r0 = row_blk + w * 32;   // this wave's 32 rows

    // ---- A fill: 2 m-tiles x 16 k-windows, fp32->bf16 once ----
    s16x8 a[2][16];
    {
        const float* ap = A + (size_t)(r0 + ml) * H_ + q * 8;
#pragma unroll
        for (int kw = 0; kw < 16; ++kw) {
#pragma unroll
            for (int t = 0; t < 2; ++t) {
                const float* p = ap + (size_t)t * 16 * H_ + kw * 32;
                float4 x = *(const float4*)p;
                float4 y = *(const float4*)(p + 4);
                a[t][kw] = cvt8(x, y);
            }
        }
    }

    // coverage per C-row (C layout: col=ml, row=q*4+reg)
    float cv[2][4];
#pragma unroll
    for (int t = 0; t < 2; ++t)
#pragma unroll
        for (int r = 0; r < 4; ++r)
            cv[t][r] = cover[r0 + t * 16 + q * 4 + r];

    // ---- B staging coords (thread t covers n_local=t>>2, chunks c=(t&3)+4j)
    const int sn = tid >> 2;         // n_local 0..63
    const int sq = tid & 3;          // q of staged chunk
    const int sv = sn >> 4;          // n-tile
    const int sml = sn & 15;
    short* sdst0 = Bs + sv * 512 + (sq * 16 + (sml ^ (sq << 1))) * 8;
    // read-side fragment base within a (kw,v) macro-chunk
    const int fb = (q * 16 + (ml ^ (q << 1))) * 8;

    float ecur[2][4] = {};

    for (int ph = 0; ph < NPH; ++ph) {
        const short* sg = Bt + ((size_t)ph * BN + sn) * H_ + sq * 8;
        if (ph) __syncthreads();  // prior phase's reads done
#pragma unroll
        for (int hv = 0; hv < 2; ++hv) {
            s16x8 tmp[8];
#pragma unroll
            for (int j = 0; j < 8; ++j)
                tmp[j] = *(const s16x8*)(sg + (hv * 8 + j) * 32);
#pragma unroll
            for (int j = 0; j < 8; ++j)
                *(s16x8*)(sdst0 + (size_t)(hv * 8 + j) * 2048) = tmp[j];
        }
        __syncthreads();

        // per-phase column params
        float wc[4], vv[4], dd[4];
#pragma unroll
        for (int v = 0; v < 4; ++v) {
            const int n = ph * BN + v * 16 + ml;
            wc[v] = Wc[n];
            vv[v] = vw[n];
            dd[v] = D[b * H_ + n];
        }

        f32x4 acc[2][4];
#pragma unroll
        for (int t = 0; t < 2; ++t)
#pragma unroll
            for (int v = 0; v < 4; ++v) acc[t][v] = (f32x4)0.0f;

#pragma unroll
        for (int kw = 0; kw < 16; ++kw) {
            s16x8 bfr[4];
#pragma unroll
            for (int v = 0; v < 4; ++v)
                bfr[v] = *(const s16x8*)&Bs[kw * 2048 + v * 512 + fb];
#pragma unroll
            for (int v = 0; v < 4; ++v) {
                acc[0][v] = __builtin_amdgcn_mfma_f32_16x16x32_bf16(
                    a[0][kw], bfr[v], acc[0][v], 0, 0, 0);
                acc[1][v] = __builtin_amdgcn_mfma_f32_16x16x32_bf16(
                    a[1][kw], bfr[v], acc[1][v], 0, 0, 0);
            }
        }

        // accumulate e partials: x = acc + cov*Wc + D; e += vw*tanh(x)
#pragma unroll
        for (int t = 0; t < 2; ++t) {
#pragma unroll
            for (int v = 0; v < 4; ++v) {
                ecur[t][0] += vv[v] * fast_tanh(acc[t][v].x + fmaf(cv[t][0], wc[v], dd[v]));
                ecur[t][1] += vv[v] * fast_tanh(acc[t][v].y + fmaf(cv[t][1], wc[v], dd[v]));
                ecur[t][2] += vv[v] * fast_tanh(acc[t][v].z + fmaf(cv[t][2], wc[v], dd[v]));
                ecur[t][3] += vv[v] * fast_tanh(acc[t][v].w + fmaf(cv[t][3], wc[v], dd[v]));
            }
        }
    }

    // final cross-lane (ml) reduction and store
#pragma unroll
    for (int t = 0; t < 2; ++t) {
        float p0 = ecur[t][0], p1 = ecur[t][1], p2 = ecur[t][2], p3 = ecur[t][3];
#pragma unroll
        for (int s = 1; s < 16; s <<= 1) {
            p0 += __shfl_xor(p0, s, 64);
            p1 += __shfl_xor(p1, s, 64);
            p2 += __shfl_xor(p2, s, 64);
            p3 += __shfl_xor(p3, s, 64);
        }
        if (ml == 0) {
            float4 st = {p0, p1, p2, p3};
            *(float4*)&e_t[r0 + t * 16 + q * 4] = st;
        }
    }
}

__global__ __launch_bounds__(256) void softmax_kernel(
    const float* __restrict__ e_t, const float* __restrict__ cover,
    const float* __restrict__ vb, float* __restrict__ out) {
    const int b = blockIdx.x;
    const int tid = threadIdx.x;
    const float vbv = vb[0];

    float e[8];
    float mx = -1e30f;
#pragma unroll
    for (int r = 0; r < 8; ++r) {
        e[r] = e_t[b * S_ + r * 256 + tid] + vbv;
        mx = fmaxf(mx, e[r]);
    }
#pragma unroll
    for (int off = 32; off >= 1; off >>= 1) mx = fmaxf(mx, __shfl_xor(mx, off, 64));

    __shared__ float sm[4], ss[4], sbc[2];
    const int wid = tid >> 6, lane = tid & 63;
    if (lane == 0) sm[wid] = mx;
    __syncthreads();
    if (tid == 0) sbc[0] = fmaxf(fmaxf(sm[0], sm[1]), fmaxf(sm[2], sm[3]));
    __syncthreads();
    mx = sbc[0];

    float ex[8];
    float sum = 0.0f;
#pragma unroll
    for (int r = 0; r < 8; ++r) {
        ex[r] = __expf(e[r] - mx);
        sum += ex[r];
    }
#pragma unroll
    for (int off = 32; off >= 1; off >>= 1) sum += __shfl_xor(sum, off, 64);
    if (lane == 0) ss[wid] = sum;
    __syncthreads();
    if (tid == 0) sbc[1] = ss[0] + ss[1] + ss[2] + ss[3];
    __syncthreads();
    const float inv = 1.0f / sbc[1];

#pragma unroll
    for (int r = 0; r < 8; ++r) {
        const int s = r * 256 + tid;
        const float a = ex[r] * inv;
        out[b * S_ + s] = a;                           // a_t
        out[M_ + b * S_ + s] = cover[b * S_ + s] + a;  // sum_coverage
    }
}

extern "C" void kernel_launch(void* const* d_in, const int* in_sizes, int n_in,
                              void* d_out, int out_size, void* d_ws, size_t ws_size,
                              hipStream_t stream) {
    const float* enc = (const float*)d_in[0];
    const float* dh  = (const float*)d_in[1];
    const float* cov = (const float*)d_in[2];
    const float* Wh  = (const float*)d_in[3];
    const float* bh  = (const float*)d_in[4];
    const float* Ws  = (const float*)d_in[5];
    const float* bs  = (const float*)d_in[6];
    const float* Wc  = (const float*)d_in[7];
    const float* bc  = (const float*)d_in[8];
    const float* vw  = (const float*)d_in[9];
    const float* vb  = (const float*)d_in[10];
    float* out = (float*)d_out;

    float* e_t  = (float*)d_ws;              // M_ floats
    float* Dws  = e_t + M_;                  // B_*H_ floats
    short* Whbt = (short*)(Dws + B_ * H_);   // H_*H_ bf16

    transpose_cast<<<dim3(H_ / 32, H_ / 32), 256, 0, stream>>>(Wh, Whbt);
    dec_kernel<<<B_, 512, 0, stream>>>(dh, Ws, bs, bh, bc, Dws);
    gemm_fused<<<M_ / RPB, 256, 0, stream>>>(enc, Whbt, cov, Wc, vw, Dws, e_t);
    softmax_kernel<<<B_, 256, 0, stream>>>(e_t, cov, vb, out);
}